// Round 1
// 550.995 us; speedup vs baseline: 1.0768x; 1.0768x over previous
//
#include <hip/hip_runtime.h>
#include <math.h>

// ---------------- problem constants ----------------
#define NV    50257
#define OUT_M 402056            // 8*50257
#define OUT_A 402568            // + 8*64
#define SCALE 0.125f            // 1/sqrt(64)

// ---------------- ws layout (float offsets) ----------------
#define WS_Q      0             // [8][64][64]
#define WS_HTR    32768         // [1024][8]
#define WS_S      40960         // [64][64]  S = WG Sigma WG^T
#define WS_TV     45056         // [64]
#define WS_C0     45120         // [1] (pad 8)
#define WS_IU     45128         // (unused now)
#define WS_HLIE   47144         // [8][64]
#define WS_W1     47656         // [8][64]
#define WS_S0     48168         // (unused now)
#define WS_GH     48176         // [8]
#define WS_WMAT   48192         // [8][64][64]  W = Q G Q^T
#define WS_SC     80960         // [8][256] scores
#define WS_WB     83008         // [8][64]
#define WS_CONSTB 83520         // [8]
#define WS_GAMMA  83528         // [8]
#define WS_CT     83536         // [8][64]
#define WS_P6     84048         // [8][4][20] top-k partials

// =====================================================================
// K12: blocks 0..7 -> Gauss-Jordan (I-A)Q=(I+A), htr, then the whole
//      former K2 per-batch chain (q_t/h_lie GEMVs, qkv, ghl, w1,
//      gamma_h, W = Q G Q^T) with Q consumed directly from LDS.
//      block 8 -> S = WG Sigma WG^T, tvec, c0 (reuses Ash/Gsh LDS).
//      S0 path removed: softmax is shift-invariant in the per-batch
//      constant, so qkb and hGh need not be computed at all.
// =====================================================================
__global__ __launch_bounds__(256) void k12_prep(
    const float* __restrict__ h_t, const float* __restrict__ A_t,
    const float* __restrict__ G_t,
    const float* __restrict__ WG_w, const float* __restrict__ WG_b,
    const float* __restrict__ Sigma_inv,
    const float* __restrict__ WQ_w, const float* __restrict__ WQ_b,
    const float* __restrict__ WK_w, const float* __restrict__ WK_b,
    const float* __restrict__ wgamma_w,
    const float* __restrict__ hlie_w, const float* __restrict__ hlie_b,
    float* __restrict__ ws)
{
    __shared__ float Ash[64][65];
    __shared__ float Gsh[64][65];
    __shared__ float hsh[1024];
    __shared__ float piv[2][132];
    __shared__ float fr[2][64];
    __shared__ float dsh[64];
    __shared__ float part[4][64], partb[4][64];
    __shared__ float qt[64], hl[64], qkv[64], ghl[64], v0[64];
    __shared__ float red64[4];
    __shared__ float scal[1];

    const int tid = threadIdx.x;
    const int blk = blockIdx.x;

    if (blk == 8) {
        // ---- S = WG Sigma WG^T, tvec, c0. Ash<=Wsc, Gsh<=Wr, hsh<=sig,bg
        const int a   = tid & 63;
        const int cb8 = __builtin_amdgcn_readfirstlane(tid >> 6);
        float* sig = hsh;
        float* bg  = hsh + 64;
        if (tid < 64) { sig[tid] = Sigma_inv[tid]; bg[tid] = WG_b[tid]; }
        __syncthreads();
        for (int idx = tid; idx < 4096; idx += 256) {
            int r = idx >> 6, c = idx & 63;
            float wv = WG_w[idx];
            Gsh[r][c] = wv;            // Wr
            Ash[r][c] = wv * sig[c];   // Wsc
        }
        __syncthreads();
        float t8[16];
        #pragma unroll
        for (int j = 0; j < 16; ++j) t8[j] = 0.0f;
        for (int p = 0; p < 64; ++p) {
            float wv = Ash[a][p];
            #pragma unroll
            for (int jj = 0; jj < 16; ++jj) t8[jj] = fmaf(wv, Gsh[cb8*16 + jj][p], t8[jj]);
        }
        #pragma unroll
        for (int jj = 0; jj < 16; ++jj)
            ws[WS_S + a*64 + cb8*16 + jj] = t8[jj];
        if (cb8 == 0) {
            float s = 0.0f;
            for (int p = 0; p < 64; ++p) s += Ash[a][p] * bg[p];
            ws[WS_TV + a] = 2.0f * s;
        }
        if (tid == 0) {
            float c0 = 0.0f;
            for (int p = 0; p < 64; ++p) c0 += sig[p] * bg[p] * bg[p];
            ws[WS_C0] = c0;
        }
        return;
    }

    const int b  = blk;
    const int i  = tid & 63;
    const int cb = __builtin_amdgcn_readfirstlane(tid >> 6);
    const int col0 = cb * 16;

    // stage A, G, h (htr written on the way)
    for (int idx = tid; idx < 4096; idx += 256) {
        int r = idx >> 6, c = idx & 63;
        Ash[r][c] = A_t[b*4096 + idx];
        Gsh[r][c] = G_t[b*4096 + idx];
    }
    for (int k = tid; k < 1024; k += 256) {
        float hv = h_t[b*1024 + k];
        hsh[k] = hv;
        ws[WS_HTR + k*8 + b] = hv;
    }
    __syncthreads();

    // ---- Gauss-Jordan: thread (i, cb) holds 32 cols of [I-A | I+A]
    float w[32];
    if (cb < 2) {
        #pragma unroll
        for (int jj = 0; jj < 32; ++jj) {
            int j = cb*32 + jj;
            w[jj] = (i == j ? 1.0f : 0.0f) - Ash[i][j];
        }
    } else {
        #pragma unroll
        for (int jj = 0; jj < 32; ++jj) {
            int j = (cb - 2)*32 + jj;
            w[jj] = (i == j ? 1.0f : 0.0f) + Ash[i][j];
        }
    }
    __syncthreads();

    #pragma unroll
    for (int k = 0; k < 64; ++k) {
        const int kb  = k >> 5;
        const int sel = k & 1;
        if (cb == kb) fr[sel][i] = w[k & 31];
        if (i == k) {
            #pragma unroll
            for (int q4 = 0; q4 < 8; ++q4)
                *(float4*)&piv[sel][cb*32 + q4*4] =
                    make_float4(w[q4*4], w[q4*4+1], w[q4*4+2], w[q4*4+3]);
        }
        __syncthreads();
        float pk = piv[sel][k];
        float f = (i == k) ? 0.0f : (fr[sel][i] / pk);
        #pragma unroll
        for (int jj = 0; jj < 32; ++jj)
            w[jj] -= f * piv[sel][cb*32 + jj];
    }

    if (cb == (i >> 5)) dsh[i] = w[i & 31];
    __syncthreads();
    if (cb >= 2) {
        float dinv = 1.0f / dsh[i];
        #pragma unroll
        for (int jj = 0; jj < 32; ++jj)
            Ash[i][(cb - 2)*32 + jj] = w[jj] * dinv;   // Ash := Q
    }
    __syncthreads();
    for (int idx = tid; idx < 4096; idx += 256)
        ws[WS_Q + b*4096 + idx] = Ash[idx >> 6][idx & 63];

    // ---- former K2: GEMVs from h (2-way ILP split)
    {
        float aq0 = 0, aq1 = 0, ah0 = 0, ah1 = 0, ag0 = 0, ag1 = 0;
        #pragma unroll 8
        for (int kk = 0; kk < 256; kk += 2) {
            int k = cb*256 + kk;
            float hv0 = hsh[k], hv1 = hsh[k + 1];
            aq0 = fmaf(hv0, WQ_w[k*64 + i], aq0);
            aq1 = fmaf(hv1, WQ_w[(k+1)*64 + i], aq1);
            ah0 = fmaf(hv0, hlie_w[k*64 + i], ah0);
            ah1 = fmaf(hv1, hlie_w[(k+1)*64 + i], ah1);
            ag0 = fmaf(hv0, wgamma_w[k], ag0);
            ag1 = fmaf(hv1, wgamma_w[k+1], ag1);
        }
        part[cb][i] = aq0 + aq1;
        partb[cb][i] = ah0 + ah1;
        if (i == 0) red64[cb] = ag0 + ag1;
    }
    __syncthreads();
    if (tid < 64) {
        qt[tid] = part[0][tid]+part[1][tid]+part[2][tid]+part[3][tid] + WQ_b[tid];
        hl[tid] = partb[0][tid]+partb[1][tid]+partb[2][tid]+partb[3][tid] + hlie_b[tid];
    }
    if (tid == 0) scal[0] = red64[0]+red64[1]+red64[2]+red64[3];   // gamma_h
    __syncthreads();
    // qkvec = WK q_t
    {
        float acc = 0;
        #pragma unroll
        for (int jj = 0; jj < 16; ++jj)
            acc = fmaf(WK_w[i*64 + col0 + jj], qt[col0 + jj], acc);
        part[cb][i] = acc;
    }
    __syncthreads();
    if (tid < 64) qkv[tid] = part[0][tid]+part[1][tid]+part[2][tid]+part[3][tid];
    __syncthreads();
    // ghl = G hl
    {
        float acc = 0;
        #pragma unroll
        for (int jj = 0; jj < 16; ++jj)
            acc = fmaf(Gsh[i][col0 + jj], hl[col0 + jj], acc);
        part[cb][i] = acc;
    }
    __syncthreads();
    if (tid < 64) {
        ghl[tid] = part[0][tid]+part[1][tid]+part[2][tid]+part[3][tid];
        v0[tid]  = SCALE*qkv[tid] + ghl[tid];
    }
    __syncthreads();
    // w1 = Q v0
    {
        float acc = 0;
        #pragma unroll
        for (int jj = 0; jj < 16; ++jj)
            acc = fmaf(Ash[i][col0 + jj], v0[col0 + jj], acc);
        part[cb][i] = acc;
    }
    __syncthreads();
    if (tid < 64) {
        ws[WS_W1 + b*64 + tid]   = part[0][tid]+part[1][tid]+part[2][tid]+part[3][tid];
        ws[WS_HLIE + b*64 + tid] = hl[tid];
    }
    if (tid == 0) ws[WS_GH + b] = scal[0];
    // T = Q G into regs
    float t[16];
    #pragma unroll
    for (int j = 0; j < 16; ++j) t[j] = 0;
    for (int r = 0; r < 64; ++r) {
        float qv = Ash[i][r];
        #pragma unroll
        for (int j = 0; j < 16; ++j) t[j] = fmaf(qv, Gsh[r][col0 + j], t[j]);
    }
    __syncthreads();
    #pragma unroll
    for (int j = 0; j < 16; ++j) Gsh[i][col0 + j] = t[j];   // Gsh := T
    __syncthreads();
    // W = T Q^T
    float w2r[16];
    #pragma unroll
    for (int j = 0; j < 16; ++j) w2r[j] = 0;
    for (int q = 0; q < 64; ++q) {
        float tv = Gsh[i][q];
        #pragma unroll
        for (int j = 0; j < 16; ++j) w2r[j] = fmaf(tv, Ash[col0 + j][q], w2r[j]);
    }
    #pragma unroll
    for (int j = 0; j < 16; ++j)
        ws[WS_WMAT + b*4096 + (col0 + j)*64 + i] = w2r[j];
}

// =====================================================================
// K3: 32 blocks = (b, quarter). scores via b W b^T from LDS.
//     (S0 constant dropped — softmax shift-invariant.)
// =====================================================================
__global__ __launch_bounds__(256) void k3_scores(
    const float* __restrict__ B_t, float* __restrict__ ws)
{
    __shared__ float Bsh[64][65];
    __shared__ float Wsh[64][64];
    __shared__ float w1sh[64];
    __shared__ float part[4][64];
    const int b = blockIdx.x >> 2, q4 = blockIdx.x & 3;
    const int tid = threadIdx.x, lane = tid & 63;
    const int gu = __builtin_amdgcn_readfirstlane(tid >> 6);
    const int col0 = gu * 16;
    for (int idx = tid; idx < 4096; idx += 256) {
        int r = idx >> 6, c = idx & 63;
        Bsh[r][c] = B_t[b*16384 + (q4*64 + r)*64 + c];
        Wsh[r][c] = ws[WS_WMAT + b*4096 + idx];
    }
    if (tid < 64) w1sh[tid] = ws[WS_W1 + b*64 + tid];
    __syncthreads();
    float t[16];
    #pragma unroll
    for (int j = 0; j < 16; ++j) t[j] = 0;
    for (int p = 0; p < 64; ++p) {
        float bv = Bsh[lane][p];
        #pragma unroll
        for (int j = 0; j < 16; ++j) t[j] = fmaf(bv, Wsh[p][col0 + j], t[j]);
    }
    float ps = 0;
    #pragma unroll
    for (int j = 0; j < 16; ++j) ps += (w1sh[col0+j] - 0.5f*t[j]) * Bsh[lane][col0+j];
    part[gu][lane] = ps;
    __syncthreads();
    if (tid < 64)
        ws[WS_SC + b*256 + q4*64 + tid] =
            part[0][tid]+part[1][tid]+part[2][tid]+part[3][tid];
}

// =====================================================================
// K4: per batch: softmax(alpha), c chain, g_proj (coalesced g staging),
//     gamma, w_b.
// =====================================================================
__global__ __launch_bounds__(256) void k4_mid(
    const float* __restrict__ A_t, const float* __restrict__ B_t,
    const float* __restrict__ WV_w, const float* __restrict__ WV_b,
    const float* __restrict__ WC_w, const float* __restrict__ WC_b,
    const float* __restrict__ WG_w, const float* __restrict__ WG_b,
    const float* __restrict__ wgamma_w, const float* __restrict__ wgamma_b,
    const float* __restrict__ gdown_w, const float* __restrict__ Sigma_inv,
    float* __restrict__ ws)
{
    __shared__ float alpha[256], rr[256];
    __shared__ float part[4][64];
    __shared__ float cBr[64], cB[64], ct[64], cw[64], crot[64], gp[64], uv[64];
    __shared__ float gsh[2016];
    const int b = blockIdx.x, tid = threadIdx.x, lane = tid & 63;
    const int gu = __builtin_amdgcn_readfirstlane(tid >> 6);
    const int col0 = gu * 16;
    const float* Qb = ws + WS_Q + b*4096;

    // stage upper-tri g via coalesced A read (row-major triu order)
    for (int idx = tid; idx < 4096; idx += 256) {
        int i2 = idx >> 6, j2 = idx & 63;
        if (j2 > i2) {
            int s = i2*63 - ((i2*(i2-1)) >> 1) + (j2 - i2 - 1);
            gsh[s] = A_t[b*4096 + idx];
        }
    }
    float sv = ws[WS_SC + b*256 + tid];
    rr[tid] = sv; __syncthreads();
    for (int off = 128; off > 0; off >>= 1) { if (tid < off) rr[tid] = fmaxf(rr[tid], rr[tid+off]); __syncthreads(); }
    float smax = rr[0]; __syncthreads();
    float e = expf(sv - smax);
    rr[tid] = e; __syncthreads();
    for (int off = 128; off > 0; off >>= 1) { if (tid < off) rr[tid] += rr[tid+off]; __syncthreads(); }
    float den = rr[0]; __syncthreads();
    alpha[tid] = e / den;
    __syncthreads();
    // cB_raw = alpha @ B
    {
        float acc = 0;
        for (int nn = 0; nn < 64; ++nn) {
            int n = gu*64 + nn;
            acc = fmaf(alpha[n], B_t[b*16384 + n*64 + lane], acc);
        }
        part[gu][lane] = acc;
    }
    __syncthreads();
    if (tid < 64) cBr[tid] = part[0][tid]+part[1][tid]+part[2][tid]+part[3][tid];
    __syncthreads();
    // cB = cBr @ Q
    {
        float acc = 0;
        #pragma unroll
        for (int pp = 0; pp < 16; ++pp) { int p = col0+pp; acc = fmaf(cBr[p], Qb[p*64+lane], acc); }
        part[gu][lane] = acc;
    }
    __syncthreads();
    if (tid < 64) cB[tid] = part[0][tid]+part[1][tid]+part[2][tid]+part[3][tid];
    __syncthreads();
    // c_t = cB @ WV + bv
    {
        float acc = 0;
        #pragma unroll
        for (int pp = 0; pp < 16; ++pp) { int p = col0+pp; acc = fmaf(cB[p], WV_w[p*64+lane], acc); }
        part[gu][lane] = acc;
    }
    __syncthreads();
    if (tid < 64) {
        float v = part[0][tid]+part[1][tid]+part[2][tid]+part[3][tid] + WV_b[tid];
        ct[tid] = v; ws[WS_CT + b*64 + tid] = v;
    }
    __syncthreads();
    // cw = c_t @ WC + cb
    {
        float acc = 0;
        #pragma unroll
        for (int pp = 0; pp < 16; ++pp) { int p = col0+pp; acc = fmaf(ct[p], WC_w[p*64+lane], acc); }
        part[gu][lane] = acc;
    }
    __syncthreads();
    if (tid < 64) cw[tid] = part[0][tid]+part[1][tid]+part[2][tid]+part[3][tid] + WC_b[tid];
    __syncthreads();
    // crot = cw @ Q
    {
        float acc = 0;
        #pragma unroll
        for (int pp = 0; pp < 16; ++pp) { int p = col0+pp; acc = fmaf(cw[p], Qb[p*64+lane], acc); }
        part[gu][lane] = acc;
    }
    __syncthreads();
    if (tid < 64) crot[tid] = part[0][tid]+part[1][tid]+part[2][tid]+part[3][tid];
    __syncthreads();
    // g_proj = g @ gdown (g from LDS), gamma partials (2-way ILP split)
    {
        float accp0 = 0, accp1 = 0, accg0 = 0, accg1 = 0;
        #pragma unroll 4
        for (int ss = 0; ss < 504; ss += 2) {
            int s = gu*504 + ss;
            float av0 = gsh[s], av1 = gsh[s + 1];
            accp0 = fmaf(av0, gdown_w[s*64 + lane], accp0);
            accp1 = fmaf(av1, gdown_w[(s+1)*64 + lane], accp1);
            accg0 = fmaf(av0, wgamma_w[1088 + s], accg0);
            accg1 = fmaf(av1, wgamma_w[1089 + s], accg1);
        }
        part[gu][lane] = accp0 + accp1;
        if (lane == 0) rr[gu] = accg0 + accg1;
    }
    if (tid < 64) rr[64 + tid] = ct[tid] * wgamma_w[1024 + tid];
    __syncthreads();
    if (tid < 64) {
        float g = part[0][tid]+part[1][tid]+part[2][tid]+part[3][tid];
        gp[tid] = g; uv[tid] = 2.0f * Sigma_inv[tid] * g;
    }
    if (tid == 0) {
        float gc = 0; for (int j = 0; j < 64; ++j) gc += rr[64 + j];
        float z = ws[WS_GH + b] + gc + rr[0]+rr[1]+rr[2]+rr[3] + wgamma_b[0];
        ws[WS_GAMMA + b] = 1.0f / (1.0f + expf(-z));
    }
    __syncthreads();
    // w_b = scale*crot + WG u ; const_b = bg.u - sum gp^2 sig
    {
        float acc = 0;
        #pragma unroll
        for (int pp = 0; pp < 16; ++pp) { int p = col0+pp; acc = fmaf(WG_w[lane*64+p], uv[p], acc); }
        part[gu][lane] = acc;
    }
    if (tid < 64) rr[tid] = WG_b[tid]*uv[tid] - gp[tid]*gp[tid]*Sigma_inv[tid];
    __syncthreads();
    if (tid < 64)
        ws[WS_WB + b*64 + tid] = SCALE*crot[tid]
            + part[0][tid]+part[1][tid]+part[2][tid]+part[3][tid];
    if (tid == 0) { float s = 0; for (int j = 0; j < 64; ++j) s += rr[j]; ws[WS_CONSTB + b] = s; }
}

// =====================================================================
// K5: fused logits. 256 threads/block, 128 v per block (2 threads/v).
//     Phase 1: sv quadratic split across halves + gd from staged Esh
//     (E read ONCE from HBM). Phase 2: 2-way k-split WO stream with h
//     broadcast from LDS, cross-half LDS reduce.
// =====================================================================
#define KU 16
__global__ __launch_bounds__(256) void k5_logits(
    const float* __restrict__ E, const float* __restrict__ WO_w,
    const float* __restrict__ ws, float* __restrict__ out)
{
    __shared__ float smem[14544];   // 58.2 KB, two-phase reuse -> 2 blocks/CU
    const int tid  = threadIdx.x;
    const int half = tid >> 7;      // 0/1 : k-range + work split
    const int vt   = tid & 127;
    const int vb = blockIdx.x * 128;
    const int v = vb + vt;
    const bool vok = v < NV;
    const int vv = vok ? v : NV - 1;

    // phase 1 partition (persistent tail region at 12544+)
    float* Esh  = smem;            // [128][66]
    float* Ssh  = smem + 8448;     // [64][64]
    float* tvsh = smem + 12544;    // [64]
    float* wbsh = smem + 12608;    // [8][64]
    float* gmsh = smem + 13120;    // [8]
    float* cbsh = smem + 13128;    // [8]
    float* svsh = smem + 13136;    // [2][128]   (persists)
    float* gdsh = smem + 13392;    // [128][9]   (persists)

    for (int idx = tid; idx < 2048; idx += 256) {
        int r = idx >> 4, c4 = (idx & 15) * 4;
        int vr = vb + r; if (vr >= NV) vr = NV - 1;
        float4 e4 = *(const float4*)(E + (size_t)vr * 64 + c4);
        float* dst = Esh + r*66 + c4;
        dst[0] = e4.x; dst[1] = e4.y; dst[2] = e4.z; dst[3] = e4.w;
    }
    for (int idx = tid; idx < 4096; idx += 256) Ssh[idx] = ws[WS_S + idx];
    for (int idx = tid; idx < 512; idx += 256) wbsh[idx] = ws[WS_WB + idx];
    if (tid < 64) tvsh[tid] = ws[WS_TV + tid];
    if (tid < 8) { gmsh[tid] = ws[WS_GAMMA + tid]; cbsh[tid] = ws[WS_CONSTB + tid]; }
    __syncthreads();
    {
        const float* er = Esh + vt*66;
        // sv partial: this half does 2 of the 4 jb column-blocks
        float sv = (half == 0) ? ws[WS_C0] : 0.0f;
        #pragma unroll
        for (int jj = 0; jj < 2; ++jj) {
            const int jb = half*2 + jj;
            float t[16];
            #pragma unroll
            for (int j = 0; j < 16; ++j) t[j] = 0.0f;
            for (int p = 0; p < 64; ++p) {
                float ep = er[p];
                #pragma unroll
                for (int j = 0; j < 16; ++j)
                    t[j] = fmaf(ep, Ssh[p*64 + jb*16 + j], t[j]);
            }
            #pragma unroll
            for (int j = 0; j < 16; ++j)
                sv += (t[j] + tvsh[jb*16 + j]) * er[jb*16 + j];
        }
        svsh[half*128 + vt] = sv;
        // gd: this half does 4 of the 8 batches, E row from LDS
        const float* w0 = wbsh + (half*4    )*64;
        const float* w1 = wbsh + (half*4 + 1)*64;
        const float* w2 = wbsh + (half*4 + 2)*64;
        const float* w3 = wbsh + (half*4 + 3)*64;
        float g0 = 0, g1 = 0, g2 = 0, g3 = 0;
        #pragma unroll 8
        for (int p = 0; p < 64; ++p) {
            float ep = er[p];
            g0 = fmaf(ep, w0[p], g0); g1 = fmaf(ep, w1[p], g1);
            g2 = fmaf(ep, w2[p], g2); g3 = fmaf(ep, w3[p], g3);
        }
        float* gr = gdsh + vt*9 + half*4;
        gr[0] = g0; gr[1] = g1; gr[2] = g2; gr[3] = g3;
    }
    __syncthreads();
    // phase 2 partition (overlaps dead Esh/Ssh region only)
    float* hsh   = smem;           // [1024][8]
    float* accsh = smem + 8192;    // [128][9]
    for (int idx = tid; idx < 8192; idx += 256) hsh[idx] = ws[WS_HTR + idx];
    __syncthreads();
    float acc[8];
    #pragma unroll
    for (int bb = 0; bb < 8; ++bb) acc[bb] = 0.0f;
    {
        const float* wo = WO_w + (size_t)(half * 512) * NV + vv;
        const float* hb = hsh + half*512*8;
        for (int k0 = 0; k0 < 512; k0 += KU) {
            float wr[KU];
            #pragma unroll
            for (int u = 0; u < KU; ++u) wr[u] = wo[(size_t)(k0 + u) * NV];
            #pragma unroll
            for (int u = 0; u < KU; ++u) {
                const float* hp = hb + (k0 + u)*8;
                #pragma unroll
                for (int bb = 0; bb < 8; ++bb) acc[bb] = fmaf(hp[bb], wr[u], acc[bb]);
            }
        }
    }
    if (half == 1) {
        float* ar = accsh + vt*9;
        #pragma unroll
        for (int bb = 0; bb < 8; ++bb) ar[bb] = acc[bb];
    }
    __syncthreads();
    if (half == 0 && vok) {
        const float* ar = accsh + vt*9;
        const float* gr = gdsh + vt*9;
        float svt = svsh[vt] + svsh[128 + vt];
        #pragma unroll
        for (int bb = 0; bb < 8; ++bb) {
            float gl = gr[bb] + cbsh[bb] - svt;
            out[bb*NV + v] = fmaf(gmsh[bb], gl, acc[bb] + ar[bb]);
        }
    }
}

// =====================================================================
// K6a: 32 blocks = (b, quarter): partial top-8 + rescalable softmax sums
// =====================================================================
#define NQ 12565
__global__ __launch_bounds__(256) void k6a_scan(
    const float* __restrict__ outl, float* __restrict__ ws)
{
    __shared__ float candv[2048];
    __shared__ int   candi[2048];
    __shared__ float redv[256];
    __shared__ int   redi[256];
    __shared__ int   redo[256];
    __shared__ float sred[256];
    __shared__ float t8v[8];
    __shared__ int   t8i[8];
    __shared__ int   iscal[1];
    const int b = blockIdx.x >> 2, q = blockIdx.x & 3;
    const int tid = threadIdx.x;
    const int v0 = q * NQ;
    const int v1 = (v0 + NQ < NV) ? (v0 + NQ) : NV;
    const float* lg = outl + b*NV;

    float lv[8]; int li[8];
    #pragma unroll
    for (int u = 0; u < 8; ++u) { lv[u] = -INFINITY; li[u] = 0x7fffffff; }
    for (int v = v0 + tid; v < v1; v += 256) {
        float x = lg[v];
        if (x > lv[7]) {
            int p = 7;
            while (p > 0 && x > lv[p-1]) { lv[p] = lv[p-1]; li[p] = li[p-1]; --p; }
            lv[p] = x; li[p] = v;
        }
    }
    #pragma unroll
    for (int u = 0; u < 8; ++u) { candv[tid*8 + u] = lv[u]; candi[tid*8 + u] = li[u]; }
    __syncthreads();
    int ptr = 0;
    for (int it = 0; it < 8; ++it) {
        redv[tid] = (ptr < 8) ? candv[tid*8 + ptr] : -INFINITY;
        redi[tid] = (ptr < 8) ? candi[tid*8 + ptr] : 0x7fffffff;
        redo[tid] = tid;
        __syncthreads();
        for (int off = 128; off > 0; off >>= 1) {
            if (tid < off) {
                float ov = redv[tid + off]; int oi = redi[tid + off];
                if (ov > redv[tid] || (ov == redv[tid] && oi < redi[tid])) {
                    redv[tid] = ov; redi[tid] = oi; redo[tid] = redo[tid + off];
                }
            }
            __syncthreads();
        }
        if (tid == 0) { t8v[it] = redv[0]; t8i[it] = redi[0]; iscal[0] = redo[0]; }
        __syncthreads();
        if (tid == iscal[0]) ++ptr;
        __syncthreads();
    }
    float Mp = t8v[0];
    float s1 = 0, s2 = 0;
    for (int v = v0 + tid; v < v1; v += 256) {
        float x = lg[v];
        float ee = expf(x - Mp);
        s1 += ee; s2 += x * ee;
    }
    redv[tid] = s1; sred[tid] = s2;
    __syncthreads();
    for (int off = 128; off > 0; off >>= 1) {
        if (tid < off) { redv[tid] += redv[tid+off]; sred[tid] += sred[tid+off]; }
        __syncthreads();
    }
    if (tid == 0) {
        int base = WS_P6 + (b*4 + q)*20;
        #pragma unroll
        for (int u = 0; u < 8; ++u) { ws[base + u] = t8v[u]; ((int*)ws)[base + 8 + u] = t8i[u]; }
        ws[base + 16] = Mp; ws[base + 17] = redv[0]; ws[base + 18] = sred[0];
    }
}

// =====================================================================
// K6b: per batch: merge partials, H, E_exp, rho, mu, m_next, A_next
// =====================================================================
__global__ __launch_bounds__(256) void k6b_final(
    const float* __restrict__ h_t, const float* __restrict__ A_t,
    const float* __restrict__ E, const float* __restrict__ e_mask,
    const float* __restrict__ G_t,
    const float* __restrict__ wmu_w, const float* __restrict__ wmu_b,
    const float* __restrict__ ws, float* __restrict__ out)
{
    __shared__ float mv[32];
    __shared__ int   mi[32];
    __shared__ float t8v[8];
    __shared__ int   t8i[8];
    __shared__ float toppsh[8];
    __shared__ float redv[256];
    __shared__ float uvec[64], eexp[64], msh[64], emsh[64];
    __shared__ float scal[4];
    const int b = blockIdx.x, tid = threadIdx.x;

    if (tid < 32) {
        int base = WS_P6 + (b*4 + (tid >> 3))*20;
        mv[tid] = ws[base + (tid & 7)];
        mi[tid] = ((const int*)ws)[base + 8 + (tid & 7)];
    }
    __syncthreads();
    if (tid == 0) {
        unsigned used = 0;
        for (int it = 0; it < 8; ++it) {
            float best = -INFINITY; int bi = 0x7fffffff, bs = 0;
            for (int c = 0; c < 32; ++c) {
                if (used & (1u << c)) continue;
                float x = mv[c];
                if (x > best || (x == best && mi[c] < bi)) { best = x; bi = mi[c]; bs = c; }
            }
            used |= 1u << bs; t8v[it] = best; t8i[it] = bi;
        }
        float M = t8v[0];
        float s1 = 0, s2 = 0;
        for (int q = 0; q < 4; ++q) {
            int base = WS_P6 + (b*4 + q)*20;
            float sc_ = expf(ws[base + 16] - M);
            s1 += ws[base + 17] * sc_; s2 += ws[base + 18] * sc_;
        }
        scal[0] = M + logf(s1) - s2 / s1;       // H
        float ts = 0, tv_[8];
        #pragma unroll
        for (int u = 0; u < 8; ++u) { tv_[u] = expf(t8v[u] - M); ts += tv_[u]; }
        #pragma unroll
        for (int u = 0; u < 8; ++u) toppsh[u] = tv_[u] / ts;
    }
    __syncthreads();
    if (tid < 64) {
        float u_ = 0;
        #pragma unroll
        for (int j = 0; j < 8; ++j) u_ += toppsh[j] * E[t8i[j]*64 + tid];
        uvec[tid] = u_;
    }
    __syncthreads();
    if (tid < 64) {
        const float* Qb = ws + WS_Q + b*4096;
        float a = 0;
        for (int p = 0; p < 64; ++p) a += uvec[p] * Qb[p*64 + tid];
        eexp[tid] = a;
    }
    __syncthreads();
    {   // rho
        const float* Gb = G_t + b*4096;
        const float* HL = ws + WS_HLIE + b*64;
        float a = 0;
        #pragma unroll 4
        for (int t2 = 0; t2 < 16; ++t2) {
            int idx = tid*16 + t2;
            int p = idx >> 6, q = idx & 63;
            a += (eexp[p] - HL[p]) * Gb[idx] * (eexp[q] - HL[q]);
        }
        redv[tid] = a;
    }
    __syncthreads();
    for (int off = 128; off > 0; off >>= 1) {
        if (tid < off) redv[tid] += redv[tid + off];
        __syncthreads();
    }
    if (tid == 0) scal[1] = redv[0];
    __syncthreads();
    // mu
    float pm = 0;
    for (int k = tid; k < 1024; k += 256) pm += h_t[b*1024 + k] * wmu_w[k];
    if (tid < 64) pm += ws[WS_CT + b*64 + tid] * wmu_w[1024 + tid];
    redv[tid] = pm;
    __syncthreads();
    for (int off = 128; off > 0; off >>= 1) {
        if (tid < off) redv[tid] += redv[tid + off];
        __syncthreads();
    }
    if (tid == 0) {
        float z = redv[0] + scal[0]*wmu_w[1088] + scal[1]*wmu_w[1089] + wmu_b[0];
        scal[2] = 1.0f / (1.0f + expf(-z));
    }
    __syncthreads();
    if (tid < 64) {
        float mu = scal[2];
        float em = e_mask[b*64 + tid];
        float m = mu*em + (1.0f - mu)*eexp[tid];
        out[OUT_M + b*64 + tid] = m;
        msh[tid] = m; emsh[tid] = em;
    }
    __syncthreads();
    for (int idx = tid; idx < 4096; idx += 256) {
        int i = idx >> 6, j = idx & 63;
        out[OUT_A + b*4096 + idx] = A_t[b*4096 + idx]
            + 0.1f*(msh[i]*emsh[j] - msh[j]*emsh[i]);
    }
}

// =====================================================================
extern "C" void kernel_launch(void* const* d_in, const int* in_sizes, int n_in,
                              void* d_out, int out_size, void* d_ws, size_t ws_size,
                              hipStream_t stream)
{
    const float* h_t      = (const float*)d_in[0];
    const float* A_t      = (const float*)d_in[1];
    const float* B_t      = (const float*)d_in[2];
    const float* E        = (const float*)d_in[3];
    const float* e_mask   = (const float*)d_in[4];
    const float* G_t      = (const float*)d_in[5];
    const float* WQ_w     = (const float*)d_in[7];
    const float* WQ_b     = (const float*)d_in[8];
    const float* WK_w     = (const float*)d_in[9];
    const float* WK_b     = (const float*)d_in[10];
    const float* WV_w     = (const float*)d_in[11];
    const float* WV_b     = (const float*)d_in[12];
    const float* WC_w     = (const float*)d_in[13];
    const float* WC_b     = (const float*)d_in[14];
    const float* WO_w     = (const float*)d_in[15];
    const float* WG_w     = (const float*)d_in[16];
    const float* WG_b     = (const float*)d_in[17];
    const float* wgamma_w = (const float*)d_in[18];
    const float* wgamma_b = (const float*)d_in[19];
    const float* wmu_w    = (const float*)d_in[20];
    const float* wmu_b    = (const float*)d_in[21];
    const float* gdown_w  = (const float*)d_in[22];
    const float* Sigma_inv= (const float*)d_in[23];
    const float* hlie_w   = (const float*)d_in[24];
    const float* hlie_b   = (const float*)d_in[25];
    float* out = (float*)d_out;
    float* ws  = (float*)d_ws;

    k12_prep<<<9, 256, 0, stream>>>(h_t, A_t, G_t, WG_w, WG_b, Sigma_inv,
                                    WQ_w, WQ_b, WK_w, WK_b, wgamma_w,
                                    hlie_w, hlie_b, ws);
    k3_scores<<<32, 256, 0, stream>>>(B_t, ws);
    k4_mid<<<8, 256, 0, stream>>>(A_t, B_t, WV_w, WV_b, WC_w, WC_b, WG_w, WG_b,
                                  wgamma_w, wgamma_b, gdown_w, Sigma_inv, ws);
    k5_logits<<<393, 256, 0, stream>>>(E, WO_w, ws, out);
    k6a_scan<<<32, 256, 0, stream>>>(out, ws);
    k6b_final<<<8, 256, 0, stream>>>(h_t, A_t, E, e_mask, G_t, wmu_w, wmu_b, ws, out);
}